// Round 7
// baseline (204.567 us; speedup 1.0000x reference)
//
#include <hip/hip_runtime.h>
#include <hip/hip_bf16.h>

// HypoNerf fused MLP on MI355X (gfx950). R7 = R6 structure with:
//  - 2x2 wave grid: wave (wr,wc) owns rows [wr*64,+64) x cols [wc*128,+128).
//    Halves LDS h-fragment read traffic (was 4x duplicated across waves);
//    doubles weight L2 traffic (sequential 8KB/kt streams, L2-resident).
//  - A-fragment (h) register double-buffer across kt; weight frags pipelined
//    at half-kt granularity (wfA/wfB) + cross-layer kt=0 prefetch.
//  - no setprio (m190: negative on lockstep structures).
//  - raw barriers (no vmcnt drain) kept from R6.

#define H 256
#define MT 128
#define PE_NF 60

typedef __attribute__((ext_vector_type(8))) short s16x8;   // 8 bf16
typedef __attribute__((ext_vector_type(4))) float f32x4;   // MFMA acc

static __device__ __forceinline__ unsigned short f2bf(float v) {
  unsigned int u = __float_as_uint(v);
  return (unsigned short)((u + 0x7FFFu + ((u >> 16) & 1u)) >> 16);
}
static __device__ __forceinline__ float bf2f(unsigned short u) {
  return __uint_as_float(((unsigned int)u) << 16);
}
// swizzled 16B-chunk index within a 256-elem (32-chunk) row
static __device__ __forceinline__ int hswz(int row, int chunk) {
  return (chunk & ~7) | ((chunk ^ row) & 7);
}

// raw barrier: does NOT drain vmcnt (keeps global prefetch in flight).
static __device__ __forceinline__ void bar_raw() {
  asm volatile("s_barrier" ::: "memory");
}
static __device__ __forceinline__ void bar_lgkm() {
  asm volatile("s_waitcnt lgkmcnt(0)\n\ts_barrier" ::: "memory");
}

// ---------------------------------------------------------------------------
// Prep: wb (fp32, [K+1][H], last row bias) -> fragment-packed bf16.
// pack elem idx for (n, k):  (kt*16 + (n>>4))*512 + (kgrp*16 + (n&15))*8 + j
//   where kt=k>>5, kgrp=(k>>3)&3, j=k&7.
// ---------------------------------------------------------------------------
__global__ __launch_bounds__(256) void prep_weights(
    const float* __restrict__ wb0, const float* __restrict__ wb1,
    const float* __restrict__ wb2, const float* __restrict__ wb3,
    const float* __restrict__ wb4,
    unsigned short* __restrict__ w0p, unsigned short* __restrict__ w14p,
    float* __restrict__ biases) {
  int z = blockIdx.z;
  int li = z >> 4, b = z & 15;
  int k0 = blockIdx.x * 32;
  int n0 = blockIdx.y * 32;
  int Ks;
  const float* src;
  unsigned short* dst;
  if (li == 0) {
    Ks = 120;
    if (k0 >= 128) return;
    src = wb0 + (size_t)b * 121 * H;
    dst = w0p + (size_t)b * 32768;
  } else {
    Ks = 256;
    const float* srcs[4] = {wb1, wb2, wb3, wb4};
    src = srcs[li - 1] + (size_t)b * 257 * H;
    dst = w14p + ((size_t)(li - 1) * 16 + b) * 65536;
  }
  __shared__ float tile[32][33];
  int t = threadIdx.x;
  int tx = t & 31, ty = t >> 5;
#pragma unroll
  for (int i = 0; i < 4; ++i) {
    int k = k0 + ty + i * 8;
    tile[ty + i * 8][tx] = (k < Ks) ? src[(size_t)k * H + n0 + tx] : 0.f;
  }
  if (k0 == 0 && ty == 0)
    biases[((size_t)li * 16 + b) * H + n0 + tx] = src[(size_t)Ks * H + n0 + tx];
  __syncthreads();
  if (t < 128) {
    int nn = t & 31, kg = t >> 5;
    int n = n0 + nn;
    int kt = k0 >> 5;
    union { unsigned short us[8]; s16x8 v; } pk;
#pragma unroll
    for (int j = 0; j < 8; ++j) pk.us[j] = f2bf(tile[kg * 8 + j][nn]);
    *(s16x8*)&dst[(size_t)(kt * 16 + (n >> 4)) * 512 + (kg * 16 + (n & 15)) * 8] = pk.v;
  }
}

// ---------------------------------------------------------------------------
// One fused Linear+ReLU layer. Wave (wr,wc): rows [wr*64,+64) x cols
// [wc*128,+128).  acc[4][8]; frag(kt,ctg) at wl + (kt*16+ctg)*512 + l*8.
// A-op (weights): lane holds W^T[wc*128+ct*16+rlane][kt*32+kgrp*8 ..+7]
// B-op (h):       lane holds h[wr*64+rt*16+rlane][same k]
// C: m = wr*64+rt*16+(l&15), n = wc*128+ct*16+(l>>4)*4+reg
// wfA is caller-persistent: on entry = this layer's (kt0, half0) frags; on
// exit (non-LAST) = next layer's (kt0, half0) frags (in flight).
// ---------------------------------------------------------------------------
template <int NKT, bool LAST>
static __device__ __forceinline__ void mlp_layer(
    const unsigned short* __restrict__ wl, const unsigned short* __restrict__ wln,
    const float* __restrict__ bl, unsigned short* __restrict__ h_s,
    const int rlane, const int kgrp, const int wr, const int wc, const int l,
    s16x8 (&wfA)[4]) {
  f32x4 acc[4][8];
#pragma unroll
  for (int ct = 0; ct < 8; ++ct) {
    f32x4 bini = *(const f32x4*)(bl + wc * 128 + ct * 16 + kgrp * 4);
#pragma unroll
    for (int rt = 0; rt < 4; ++rt) acc[rt][ct] = bini;
  }

  const unsigned short* fp = wl + (size_t)(wc * 8) * 512 + l * 8;
  int aoff[4];
#pragma unroll
  for (int rt = 0; rt < 4; ++rt) aoff[rt] = (wr * 64 + rt * 16 + rlane) * 256;

  // af double-buffer: load kt=0 fragments
  s16x8 af[2][4];
  {
    const int cs = hswz(rlane, kgrp) * 8;
#pragma unroll
    for (int rt = 0; rt < 4; ++rt)
      af[0][rt] = *(const s16x8*)&h_s[aoff[rt] + cs];
  }
  s16x8 wfB[4];

#pragma unroll
  for (int kt = 0; kt < NKT; ++kt) {
    // ---- half 0: prefetch this kt's half1 weight frags; MFMA with wfA
#pragma unroll
    for (int c = 0; c < 4; ++c)
      wfB[c] = *(const s16x8*)(fp + (kt * 16 + 4 + c) * 512);
#pragma unroll
    for (int rt = 0; rt < 4; ++rt)
#pragma unroll
      for (int c = 0; c < 4; ++c)
        acc[rt][c] = __builtin_amdgcn_mfma_f32_16x16x32_bf16(
            wfA[c], af[kt & 1][rt], acc[rt][c], 0, 0, 0);

    // ---- half 1: prefetch next kt's half0 frags + next kt's af; MFMA wfB
    if (kt + 1 < NKT) {
#pragma unroll
      for (int c = 0; c < 4; ++c)
        wfA[c] = *(const s16x8*)(fp + ((kt + 1) * 16 + c) * 512);
      const int cs = hswz(rlane, (kt + 1) * 4 + kgrp) * 8;
#pragma unroll
      for (int rt = 0; rt < 4; ++rt)
        af[(kt + 1) & 1][rt] = *(const s16x8*)&h_s[aoff[rt] + cs];
    } else if (!LAST) {
      const unsigned short* fpn = wln + (size_t)(wc * 8) * 512 + l * 8;
#pragma unroll
      for (int c = 0; c < 4; ++c)
        wfA[c] = *(const s16x8*)(fpn + c * 512);
    }
#pragma unroll
    for (int rt = 0; rt < 4; ++rt)
#pragma unroll
      for (int c = 0; c < 4; ++c)
        acc[rt][c + 4] = __builtin_amdgcn_mfma_f32_16x16x32_bf16(
            wfB[c], af[kt & 1][rt], acc[rt][c + 4], 0, 0, 0);
  }
  // all issued ds_reads were consumed by MFMAs -> raw barrier (no vmcnt drain)
  bar_raw();

  // epilogue: ReLU + pack 4 bf16 -> b64 store  (h[m][n0..n0+3])
  const int sub = (kgrp & 1) * 4;
  const int cbase = wc * 16 + (kgrp >> 1);
#pragma unroll
  for (int rt = 0; rt < 4; ++rt) {
    const int m = wr * 64 + rt * 16 + rlane;
    const int rowb = m * 256;
#pragma unroll
    for (int ct = 0; ct < 8; ++ct) {
      const int cs = hswz(m, cbase + ct * 2);
      float v0 = fmaxf(acc[rt][ct][0], 0.f);
      float v1 = fmaxf(acc[rt][ct][1], 0.f);
      float v2 = fmaxf(acc[rt][ct][2], 0.f);
      float v3 = fmaxf(acc[rt][ct][3], 0.f);
      union { __hip_bfloat162 h2[2]; uint2 u; } pk;
      pk.h2[0] = __float22bfloat162_rn(float2{v0, v1});
      pk.h2[1] = __float22bfloat162_rn(float2{v2, v3});
      *(uint2*)&h_s[rowb + cs * 8 + sub] = pk.u;
    }
  }
  bar_lgkm();  // DS writes visible to all waves; vmcnt untouched
}

// ---------------------------------------------------------------------------
__global__ __launch_bounds__(256, 2) void hyponerf_main(
    const float* __restrict__ x, const float* __restrict__ rfreq,
    const float* __restrict__ wbout,
    const unsigned short* __restrict__ w0p, const unsigned short* __restrict__ w14p,
    const float* __restrict__ biases, float* __restrict__ out) {
  __shared__ __align__(16) unsigned short h_s[MT * 256];  // 65536 B
  __shared__ float fr_s[PE_NF * 3];
  __shared__ float x_s[MT * 3];
  __shared__ float wout_s[H + 1];

  // XCD-aware swizzle: 2048 blocks, 8 XCDs -> contiguous batches per XCD
  int bid = blockIdx.x;
  int logical = (bid & 7) * 256 + (bid >> 3);
  int b  = logical >> 7;
  int mt = logical & 127;

  int t = threadIdx.x;
  int w = t >> 6, l = t & 63;
  int rlane = l & 15;
  int kgrp  = l >> 4;
  int wr = w >> 1, wc = w & 1;

  const unsigned short* wl0 = w0p + (size_t)b * 32768;
  const unsigned short* wl1 = w14p + (size_t)(0 * 16 + b) * 65536;
  const unsigned short* wl2 = w14p + (size_t)(1 * 16 + b) * 65536;
  const unsigned short* wl3 = w14p + (size_t)(2 * 16 + b) * 65536;
  const unsigned short* wl4 = w14p + (size_t)(3 * 16 + b) * 65536;

  // issue layer0 (kt0, half0) weight frags NOW; hides under staging + PE
  s16x8 wfA[4];
  {
    const unsigned short* fp0 = wl0 + (size_t)(wc * 8) * 512 + l * 8;
#pragma unroll
    for (int c = 0; c < 4; ++c) wfA[c] = *(const s16x8*)(fp0 + c * 512);
  }

  const float* xg = x + ((size_t)b * 16384 + (size_t)mt * MT) * 3;
  for (int i = t; i < MT * 3; i += 256) x_s[i] = xg[i];
  for (int i = t; i < PE_NF * 3; i += 256) fr_s[i] = rfreq[i] * 20.0f;
  for (int i = t; i < H + 1; i += 256) wout_s[i] = wbout[(size_t)b * (H + 1) + i];
  bar_lgkm();   // staging visible; vmcnt NOT drained

  // ---- Gaussian PE, chunk-owned b128 stores: thread (r = t>>1, q = t&1)
  //   covers n in [q*64, q*64+64): n<60 sin, 60..119 cos(n-60), 120..127 0.
  {
    int r = t >> 1;
    int q = t & 1;
    float x0 = x_s[r * 3 + 0], x1 = x_s[r * 3 + 1], x2 = x_s[r * 3 + 2];
    int rowb = r * 256;
#pragma unroll
    for (int cc = 0; cc < 8; ++cc) {
      union { unsigned short us[8]; s16x8 v; } pk;
#pragma unroll
      for (int j = 0; j < 8; ++j) {
        int n = q * 64 + cc * 8 + j;
        float v = 0.f;
        if (n < 60) {
          float kv = x0 * fr_s[n * 3] + x1 * fr_s[n * 3 + 1] + x2 * fr_s[n * 3 + 2];
          v = __sinf(kv);
        } else if (n < 120) {
          int f = n - 60;
          float kv = x0 * fr_s[f * 3] + x1 * fr_s[f * 3 + 1] + x2 * fr_s[f * 3 + 2];
          v = __cosf(kv);
        }
        pk.us[j] = f2bf(v);
      }
      *(s16x8*)&h_s[rowb + hswz(r, q * 8 + cc) * 8] = pk.v;
    }
  }
  bar_lgkm();   // PE writes visible; layer0 frags still in flight

  // ---- 5 fused Linear+ReLU layers (wfA carries next layer's kt0/half0)
  mlp_layer<4, false>(wl0, wl1, biases + (size_t)(0 * 16 + b) * H, h_s,
                      rlane, kgrp, wr, wc, l, wfA);
  mlp_layer<8, false>(wl1, wl2, biases + (size_t)(1 * 16 + b) * H, h_s,
                      rlane, kgrp, wr, wc, l, wfA);
  mlp_layer<8, false>(wl2, wl3, biases + (size_t)(2 * 16 + b) * H, h_s,
                      rlane, kgrp, wr, wc, l, wfA);
  mlp_layer<8, false>(wl3, wl4, biases + (size_t)(3 * 16 + b) * H, h_s,
                      rlane, kgrp, wr, wc, l, wfA);
  mlp_layer<8, true >(wl4, wl4, biases + (size_t)(4 * 16 + b) * H, h_s,
                      rlane, kgrp, wr, wc, l, wfA);

  // ---- final projection: out[r] = h[r][:] . wout + bias_out
  {
    int r = t >> 1;
    int cb = (t & 1) * 16;
    int rowb = r * 256;
    float sum = 0.f;
#pragma unroll
    for (int c = 0; c < 16; ++c) {
      int ch = cb + c;
      const s16x8 hv = *(const s16x8*)&h_s[rowb + hswz(r, ch) * 8];
#pragma unroll
      for (int j = 0; j < 8; ++j)
        sum += bf2f((unsigned short)hv[j]) * wout_s[ch * 8 + j];
    }
    sum += __shfl_xor(sum, 1);
    if ((t & 1) == 0)
      out[(size_t)b * 16384 + (size_t)mt * MT + r] = sum + wout_s[H];
  }
}

// ---------------------------------------------------------------------------
extern "C" void kernel_launch(void* const* d_in, const int* in_sizes, int n_in,
                              void* d_out, int out_size, void* d_ws, size_t ws_size,
                              hipStream_t stream) {
  const float* x     = (const float*)d_in[0];
  const float* wb0   = (const float*)d_in[1];
  const float* wb1   = (const float*)d_in[2];
  const float* wb2   = (const float*)d_in[3];
  const float* wb3   = (const float*)d_in[4];
  const float* wb4   = (const float*)d_in[5];
  const float* wbout = (const float*)d_in[6];
  const float* rfreq = (const float*)d_in[7];
  float* out = (float*)d_out;

  char* ws = (char*)d_ws;
  unsigned short* w0p  = (unsigned short*)ws;                                // 16 x 32768 bf16
  unsigned short* w14p = (unsigned short*)(ws + (size_t)16 * 32768 * 2);     // 64 x 65536 bf16
  float* biases = (float*)(ws + (size_t)16 * 32768 * 2
                              + (size_t)64 * 65536 * 2);                     // [5][16][256] f32

  prep_weights<<<dim3(8, 8, 80), 256, 0, stream>>>(wb0, wb1, wb2, wb3, wb4,
                                                   w0p, w14p, biases);
  hyponerf_main<<<dim3(2048), 256, 0, stream>>>(x, rfreq, wbout, w0p, w14p,
                                                biases, out);
}

// Round 8
// 177.471 us; speedup vs baseline: 1.1527x; 1.1527x over previous
//
#include <hip/hip_runtime.h>
#include <hip/hip_bf16.h>

// HypoNerf fused MLP on MI355X (gfx950). R8 = R7 (2x2 wave grid) minus the
// af[] register double-buffer that caused R7's 113MB scratch spill.
//  - wave (wr,wc) owns rows [wr*64,+64) x cols [wc*128,+128): halves the
//    per-CU LDS h-read traffic vs R4 (which was co-critical with MFMA).
//  - afr loaded just-in-time per kt (R4-proven register budget: acc 128 +
//    wfA/wfB 32 + afr 16 < 256/wave at 2 waves/SIMD).
//  - half-kt weight pipeline wfA/wfB + cross-layer kt0 carry; raw barriers
//    (no vmcnt drain); setprio around MFMA clusters (R4 best config).

#define H 256
#define MT 128
#define PE_NF 60

typedef __attribute__((ext_vector_type(8))) short s16x8;   // 8 bf16
typedef __attribute__((ext_vector_type(4))) float f32x4;   // MFMA acc

static __device__ __forceinline__ unsigned short f2bf(float v) {
  unsigned int u = __float_as_uint(v);
  return (unsigned short)((u + 0x7FFFu + ((u >> 16) & 1u)) >> 16);
}
static __device__ __forceinline__ float bf2f(unsigned short u) {
  return __uint_as_float(((unsigned int)u) << 16);
}
// swizzled 16B-chunk index within a 256-elem (32-chunk) row
static __device__ __forceinline__ int hswz(int row, int chunk) {
  return (chunk & ~7) | ((chunk ^ row) & 7);
}

// raw barrier: does NOT drain vmcnt (keeps global prefetch in flight).
static __device__ __forceinline__ void bar_raw() {
  asm volatile("s_barrier" ::: "memory");
}
static __device__ __forceinline__ void bar_lgkm() {
  asm volatile("s_waitcnt lgkmcnt(0)\n\ts_barrier" ::: "memory");
}

// ---------------------------------------------------------------------------
// Prep: wb (fp32, [K+1][H], last row bias) -> fragment-packed bf16.
// pack elem idx for (n, k):  (kt*16 + (n>>4))*512 + (kgrp*16 + (n&15))*8 + j
//   where kt=k>>5, kgrp=(k>>3)&3, j=k&7.
// ---------------------------------------------------------------------------
__global__ __launch_bounds__(256) void prep_weights(
    const float* __restrict__ wb0, const float* __restrict__ wb1,
    const float* __restrict__ wb2, const float* __restrict__ wb3,
    const float* __restrict__ wb4,
    unsigned short* __restrict__ w0p, unsigned short* __restrict__ w14p,
    float* __restrict__ biases) {
  int z = blockIdx.z;
  int li = z >> 4, b = z & 15;
  int k0 = blockIdx.x * 32;
  int n0 = blockIdx.y * 32;
  int Ks;
  const float* src;
  unsigned short* dst;
  if (li == 0) {
    Ks = 120;
    if (k0 >= 128) return;
    src = wb0 + (size_t)b * 121 * H;
    dst = w0p + (size_t)b * 32768;
  } else {
    Ks = 256;
    const float* srcs[4] = {wb1, wb2, wb3, wb4};
    src = srcs[li - 1] + (size_t)b * 257 * H;
    dst = w14p + ((size_t)(li - 1) * 16 + b) * 65536;
  }
  __shared__ float tile[32][33];
  int t = threadIdx.x;
  int tx = t & 31, ty = t >> 5;
#pragma unroll
  for (int i = 0; i < 4; ++i) {
    int k = k0 + ty + i * 8;
    tile[ty + i * 8][tx] = (k < Ks) ? src[(size_t)k * H + n0 + tx] : 0.f;
  }
  if (k0 == 0 && ty == 0)
    biases[((size_t)li * 16 + b) * H + n0 + tx] = src[(size_t)Ks * H + n0 + tx];
  __syncthreads();
  if (t < 128) {
    int nn = t & 31, kg = t >> 5;
    int n = n0 + nn;
    int kt = k0 >> 5;
    union { unsigned short us[8]; s16x8 v; } pk;
#pragma unroll
    for (int j = 0; j < 8; ++j) pk.us[j] = f2bf(tile[kg * 8 + j][nn]);
    *(s16x8*)&dst[(size_t)(kt * 16 + (n >> 4)) * 512 + (kg * 16 + (n & 15)) * 8] = pk.v;
  }
}

// ---------------------------------------------------------------------------
// One fused Linear+ReLU layer. Wave (wr,wc): rows [wr*64,+64) x cols
// [wc*128,+128).  acc[4][8]; frag(kt,ctg) at wl + (kt*16+ctg)*512 + l*8.
// A-op (weights): lane holds W^T[wc*128+ct*16+rlane][kt*32+kgrp*8 ..+7]
// B-op (h):       lane holds h[wr*64+rt*16+rlane][same k]
// C: m = wr*64+rt*16+(l&15), n = wc*128+ct*16+(l>>4)*4+reg
// wfA is caller-persistent: on entry = this layer's (kt0, half0) frags; on
// exit (non-LAST) = next layer's (kt0, half0) frags (in flight).
// ---------------------------------------------------------------------------
template <int NKT, bool LAST>
static __device__ __forceinline__ void mlp_layer(
    const unsigned short* __restrict__ wl, const unsigned short* __restrict__ wln,
    const float* __restrict__ bl, unsigned short* __restrict__ h_s,
    const int rlane, const int kgrp, const int wr, const int wc, const int l,
    s16x8 (&wfA)[4]) {
  f32x4 acc[4][8];
#pragma unroll
  for (int ct = 0; ct < 8; ++ct) {
    f32x4 bini = *(const f32x4*)(bl + wc * 128 + ct * 16 + kgrp * 4);
#pragma unroll
    for (int rt = 0; rt < 4; ++rt) acc[rt][ct] = bini;
  }

  const unsigned short* fp = wl + (size_t)(wc * 8) * 512 + l * 8;

#pragma unroll
  for (int kt = 0; kt < NKT; ++kt) {
    // just-in-time h fragments for this kt (single buffer, R4-style)
    s16x8 afr[4];
    const int cs = hswz(rlane, kt * 4 + kgrp) * 8;
#pragma unroll
    for (int rt = 0; rt < 4; ++rt)
      afr[rt] = *(const s16x8*)&h_s[(wr * 64 + rt * 16 + rlane) * 256 + cs];

    // prefetch this kt's half1 weight frags; MFMA half0 with wfA
    s16x8 wfB[4];
#pragma unroll
    for (int c = 0; c < 4; ++c)
      wfB[c] = *(const s16x8*)(fp + (kt * 16 + 4 + c) * 512);
    __builtin_amdgcn_s_setprio(1);
#pragma unroll
    for (int rt = 0; rt < 4; ++rt)
#pragma unroll
      for (int c = 0; c < 4; ++c)
        acc[rt][c] = __builtin_amdgcn_mfma_f32_16x16x32_bf16(
            wfA[c], afr[rt], acc[rt][c], 0, 0, 0);
    __builtin_amdgcn_s_setprio(0);

    // prefetch next kt's half0 (or next layer's kt0/half0); MFMA half1
    if (kt + 1 < NKT) {
#pragma unroll
      for (int c = 0; c < 4; ++c)
        wfA[c] = *(const s16x8*)(fp + ((kt + 1) * 16 + c) * 512);
    } else if (!LAST) {
      const unsigned short* fpn = wln + (size_t)(wc * 8) * 512 + l * 8;
#pragma unroll
      for (int c = 0; c < 4; ++c)
        wfA[c] = *(const s16x8*)(fpn + c * 512);
    }
    __builtin_amdgcn_s_setprio(1);
#pragma unroll
    for (int rt = 0; rt < 4; ++rt)
#pragma unroll
      for (int c = 0; c < 4; ++c)
        acc[rt][c + 4] = __builtin_amdgcn_mfma_f32_16x16x32_bf16(
            wfB[c], afr[rt], acc[rt][c + 4], 0, 0, 0);
    __builtin_amdgcn_s_setprio(0);
  }
  // all issued ds_reads were consumed by MFMAs -> raw barrier (no vmcnt drain)
  bar_raw();

  // epilogue: ReLU + pack 4 bf16 -> b64 store  (h[m][n0..n0+3])
  const int sub = (kgrp & 1) * 4;
  const int cbase = wc * 16 + (kgrp >> 1);
#pragma unroll
  for (int rt = 0; rt < 4; ++rt) {
    const int m = wr * 64 + rt * 16 + rlane;
    const int rowb = m * 256;
#pragma unroll
    for (int ct = 0; ct < 8; ++ct) {
      const int cs = hswz(m, cbase + ct * 2);
      float v0 = fmaxf(acc[rt][ct][0], 0.f);
      float v1 = fmaxf(acc[rt][ct][1], 0.f);
      float v2 = fmaxf(acc[rt][ct][2], 0.f);
      float v3 = fmaxf(acc[rt][ct][3], 0.f);
      union { __hip_bfloat162 h2[2]; uint2 u; } pk;
      pk.h2[0] = __float22bfloat162_rn(float2{v0, v1});
      pk.h2[1] = __float22bfloat162_rn(float2{v2, v3});
      *(uint2*)&h_s[rowb + cs * 8 + sub] = pk.u;
    }
  }
  bar_lgkm();  // DS writes visible to all waves; vmcnt untouched
}

// ---------------------------------------------------------------------------
__global__ __launch_bounds__(256, 2) void hyponerf_main(
    const float* __restrict__ x, const float* __restrict__ rfreq,
    const float* __restrict__ wbout,
    const unsigned short* __restrict__ w0p, const unsigned short* __restrict__ w14p,
    const float* __restrict__ biases, float* __restrict__ out) {
  __shared__ __align__(16) unsigned short h_s[MT * 256];  // 65536 B
  __shared__ float fr_s[PE_NF * 3];
  __shared__ float x_s[MT * 3];
  __shared__ float wout_s[H + 1];

  // XCD-aware swizzle: 2048 blocks, 8 XCDs -> contiguous batches per XCD
  int bid = blockIdx.x;
  int logical = (bid & 7) * 256 + (bid >> 3);
  int b  = logical >> 7;
  int mt = logical & 127;

  int t = threadIdx.x;
  int w = t >> 6, l = t & 63;
  int rlane = l & 15;
  int kgrp  = l >> 4;
  int wr = w >> 1, wc = w & 1;

  const unsigned short* wl0 = w0p + (size_t)b * 32768;
  const unsigned short* wl1 = w14p + (size_t)(0 * 16 + b) * 65536;
  const unsigned short* wl2 = w14p + (size_t)(1 * 16 + b) * 65536;
  const unsigned short* wl3 = w14p + (size_t)(2 * 16 + b) * 65536;
  const unsigned short* wl4 = w14p + (size_t)(3 * 16 + b) * 65536;

  // issue layer0 (kt0, half0) weight frags NOW; hides under staging + PE
  s16x8 wfA[4];
  {
    const unsigned short* fp0 = wl0 + (size_t)(wc * 8) * 512 + l * 8;
#pragma unroll
    for (int c = 0; c < 4; ++c) wfA[c] = *(const s16x8*)(fp0 + c * 512);
  }

  const float* xg = x + ((size_t)b * 16384 + (size_t)mt * MT) * 3;
  for (int i = t; i < MT * 3; i += 256) x_s[i] = xg[i];
  for (int i = t; i < PE_NF * 3; i += 256) fr_s[i] = rfreq[i] * 20.0f;
  for (int i = t; i < H + 1; i += 256) wout_s[i] = wbout[(size_t)b * (H + 1) + i];
  bar_lgkm();   // staging visible; vmcnt NOT drained

  // ---- Gaussian PE, chunk-owned b128 stores: thread (r = t>>1, q = t&1)
  //   covers n in [q*64, q*64+64): n<60 sin, 60..119 cos(n-60), 120..127 0.
  {
    int r = t >> 1;
    int q = t & 1;
    float x0 = x_s[r * 3 + 0], x1 = x_s[r * 3 + 1], x2 = x_s[r * 3 + 2];
    int rowb = r * 256;
#pragma unroll
    for (int cc = 0; cc < 8; ++cc) {
      union { unsigned short us[8]; s16x8 v; } pk;
#pragma unroll
      for (int j = 0; j < 8; ++j) {
        int n = q * 64 + cc * 8 + j;
        float v = 0.f;
        if (n < 60) {
          float kv = x0 * fr_s[n * 3] + x1 * fr_s[n * 3 + 1] + x2 * fr_s[n * 3 + 2];
          v = __sinf(kv);
        } else if (n < 120) {
          int f = n - 60;
          float kv = x0 * fr_s[f * 3] + x1 * fr_s[f * 3 + 1] + x2 * fr_s[f * 3 + 2];
          v = __cosf(kv);
        }
        pk.us[j] = f2bf(v);
      }
      *(s16x8*)&h_s[rowb + hswz(r, q * 8 + cc) * 8] = pk.v;
    }
  }
  bar_lgkm();   // PE writes visible; layer0 frags still in flight

  // ---- 5 fused Linear+ReLU layers (wfA carries next layer's kt0/half0)
  mlp_layer<4, false>(wl0, wl1, biases + (size_t)(0 * 16 + b) * H, h_s,
                      rlane, kgrp, wr, wc, l, wfA);
  mlp_layer<8, false>(wl1, wl2, biases + (size_t)(1 * 16 + b) * H, h_s,
                      rlane, kgrp, wr, wc, l, wfA);
  mlp_layer<8, false>(wl2, wl3, biases + (size_t)(2 * 16 + b) * H, h_s,
                      rlane, kgrp, wr, wc, l, wfA);
  mlp_layer<8, false>(wl3, wl4, biases + (size_t)(3 * 16 + b) * H, h_s,
                      rlane, kgrp, wr, wc, l, wfA);
  mlp_layer<8, true >(wl4, wl4, biases + (size_t)(4 * 16 + b) * H, h_s,
                      rlane, kgrp, wr, wc, l, wfA);

  // ---- final projection: out[r] = h[r][:] . wout + bias_out
  {
    int r = t >> 1;
    int cb = (t & 1) * 16;
    int rowb = r * 256;
    float sum = 0.f;
#pragma unroll
    for (int c = 0; c < 16; ++c) {
      int ch = cb + c;
      const s16x8 hv = *(const s16x8*)&h_s[rowb + hswz(r, ch) * 8];
#pragma unroll
      for (int j = 0; j < 8; ++j)
        sum += bf2f((unsigned short)hv[j]) * wout_s[ch * 8 + j];
    }
    sum += __shfl_xor(sum, 1);
    if ((t & 1) == 0)
      out[(size_t)b * 16384 + (size_t)mt * MT + r] = sum + wout_s[H];
  }
}

// ---------------------------------------------------------------------------
extern "C" void kernel_launch(void* const* d_in, const int* in_sizes, int n_in,
                              void* d_out, int out_size, void* d_ws, size_t ws_size,
                              hipStream_t stream) {
  const float* x     = (const float*)d_in[0];
  const float* wb0   = (const float*)d_in[1];
  const float* wb1   = (const float*)d_in[2];
  const float* wb2   = (const float*)d_in[3];
  const float* wb3   = (const float*)d_in[4];
  const float* wb4   = (const float*)d_in[5];
  const float* wbout = (const float*)d_in[6];
  const float* rfreq = (const float*)d_in[7];
  float* out = (float*)d_out;

  char* ws = (char*)d_ws;
  unsigned short* w0p  = (unsigned short*)ws;                                // 16 x 32768 bf16
  unsigned short* w14p = (unsigned short*)(ws + (size_t)16 * 32768 * 2);     // 64 x 65536 bf16
  float* biases = (float*)(ws + (size_t)16 * 32768 * 2
                              + (size_t)64 * 65536 * 2);                     // [5][16][256] f32

  prep_weights<<<dim3(8, 8, 80), 256, 0, stream>>>(wb0, wb1, wb2, wb3, wb4,
                                                   w0p, w14p, biases);
  hyponerf_main<<<dim3(2048), 256, 0, stream>>>(x, rfreq, wbout, w0p, w14p,
                                                biases, out);
}

// Round 9
// 170.920 us; speedup vs baseline: 1.1969x; 1.0383x over previous
//
#include <hip/hip_runtime.h>
#include <hip/hip_bf16.h>

// HypoNerf fused MLP on MI355X (gfx950). R9: occupancy round.
//  - MT=64, 4096 blocks, 4 waves/block; wave wc owns all 64 rows x cols
//    [wc*64,+64): acc[4][4] = 64 acc regs -> ~155 total -> 3 waves/SIMD
//    (R4/R6/R8 all ran 2/SIMD and pinned at the ~884 TF 2-phase ceiling).
//  - both operands register-pipelined 1 kt ahead: wf[2][4] (weights, global
//    packed stream) + af[2][4] (h, LDS) -> 310cy MFMA cover per prefetch.
//  - fragment-packed weights (R4 format), cross-layer kt0 carry, raw
//    barriers (no vmcnt drain), setprio (3 drifting blocks = role diversity).

#define H 256
#define MT 64
#define PE_NF 60

typedef __attribute__((ext_vector_type(8))) short s16x8;   // 8 bf16
typedef __attribute__((ext_vector_type(4))) float f32x4;   // MFMA acc

static __device__ __forceinline__ unsigned short f2bf(float v) {
  unsigned int u = __float_as_uint(v);
  return (unsigned short)((u + 0x7FFFu + ((u >> 16) & 1u)) >> 16);
}
static __device__ __forceinline__ float bf2f(unsigned short u) {
  return __uint_as_float(((unsigned int)u) << 16);
}
// swizzled 16B-chunk index within a 256-elem (32-chunk) row
static __device__ __forceinline__ int hswz(int row, int chunk) {
  return (chunk & ~7) | ((chunk ^ row) & 7);
}

// raw barrier: does NOT drain vmcnt (keeps global prefetch in flight).
static __device__ __forceinline__ void bar_raw() {
  asm volatile("s_barrier" ::: "memory");
}
static __device__ __forceinline__ void bar_lgkm() {
  asm volatile("s_waitcnt lgkmcnt(0)\n\ts_barrier" ::: "memory");
}

// ---------------------------------------------------------------------------
// Prep: wb (fp32, [K+1][H], last row bias) -> fragment-packed bf16.
// pack elem idx for (n, k):  (kt*16 + (n>>4))*512 + (kgrp*16 + (n&15))*8 + j
//   where kt=k>>5, kgrp=(k>>3)&3, j=k&7.
// ---------------------------------------------------------------------------
__global__ __launch_bounds__(256) void prep_weights(
    const float* __restrict__ wb0, const float* __restrict__ wb1,
    const float* __restrict__ wb2, const float* __restrict__ wb3,
    const float* __restrict__ wb4,
    unsigned short* __restrict__ w0p, unsigned short* __restrict__ w14p,
    float* __restrict__ biases) {
  int z = blockIdx.z;
  int li = z >> 4, b = z & 15;
  int k0 = blockIdx.x * 32;
  int n0 = blockIdx.y * 32;
  int Ks;
  const float* src;
  unsigned short* dst;
  if (li == 0) {
    Ks = 120;
    if (k0 >= 128) return;
    src = wb0 + (size_t)b * 121 * H;
    dst = w0p + (size_t)b * 32768;
  } else {
    Ks = 256;
    const float* srcs[4] = {wb1, wb2, wb3, wb4};
    src = srcs[li - 1] + (size_t)b * 257 * H;
    dst = w14p + ((size_t)(li - 1) * 16 + b) * 65536;
  }
  __shared__ float tile[32][33];
  int t = threadIdx.x;
  int tx = t & 31, ty = t >> 5;
#pragma unroll
  for (int i = 0; i < 4; ++i) {
    int k = k0 + ty + i * 8;
    tile[ty + i * 8][tx] = (k < Ks) ? src[(size_t)k * H + n0 + tx] : 0.f;
  }
  if (k0 == 0 && ty == 0)
    biases[((size_t)li * 16 + b) * H + n0 + tx] = src[(size_t)Ks * H + n0 + tx];
  __syncthreads();
  if (t < 128) {
    int nn = t & 31, kg = t >> 5;
    int n = n0 + nn;
    int kt = k0 >> 5;
    union { unsigned short us[8]; s16x8 v; } pk;
#pragma unroll
    for (int j = 0; j < 8; ++j) pk.us[j] = f2bf(tile[kg * 8 + j][nn]);
    *(s16x8*)&dst[(size_t)(kt * 16 + (n >> 4)) * 512 + (kg * 16 + (n & 15)) * 8] = pk.v;
  }
}

// ---------------------------------------------------------------------------
// One fused Linear+ReLU layer. Wave wc: all 64 rows x cols [wc*64,+128... 64).
// acc[4][4]; frag(kt,ctg) at wl + (kt*16+ctg)*512 + l*8, ctg = wc*4+ct.
// A-op (weights): lane holds W^T[wc*64+ct*16+rlane][kt*32+kgrp*8 ..+7]
// B-op (h):       lane holds h[rt*16+rlane][same k]
// C: m = rt*16+(l&15), n = wc*64+ct*16+(l>>4)*4+reg
// wf is caller-persistent: on entry = this layer's kt0 frags; on exit
// (non-LAST) wf[0] = next layer's kt0 frags (in flight across barriers).
// ---------------------------------------------------------------------------
template <int NKT, bool LAST>
static __device__ __forceinline__ void mlp_layer(
    const unsigned short* __restrict__ wl, const unsigned short* __restrict__ wln,
    const float* __restrict__ bl, unsigned short* __restrict__ h_s,
    const int rlane, const int kgrp, const int wc, const int l,
    s16x8 (&wf)[2][4]) {
  static_assert((NKT & 1) == 0, "ping-pong parity needs even NKT");
  f32x4 acc[4][4];
#pragma unroll
  for (int ct = 0; ct < 4; ++ct) {
    f32x4 bini = *(const f32x4*)(bl + wc * 64 + ct * 16 + kgrp * 4);
#pragma unroll
    for (int rt = 0; rt < 4; ++rt) acc[rt][ct] = bini;
  }

  const unsigned short* fp = wl + (size_t)(wc * 4) * 512 + l * 8;

  // h-fragment double buffer: load kt0
  s16x8 af[2][4];
  {
    const int cs = hswz(rlane, kgrp) * 8;
#pragma unroll
    for (int rt = 0; rt < 4; ++rt)
      af[0][rt] = *(const s16x8*)&h_s[(rt * 16 + rlane) * 256 + cs];
  }

#pragma unroll
  for (int kt = 0; kt < NKT; ++kt) {
    // prefetch kt+1 operands (or next layer's kt0 weight frags)
    if (kt + 1 < NKT) {
#pragma unroll
      for (int c = 0; c < 4; ++c)
        wf[(kt + 1) & 1][c] = *(const s16x8*)(fp + ((kt + 1) * 16 + c) * 512);
      const int cs = hswz(rlane, (kt + 1) * 4 + kgrp) * 8;
#pragma unroll
      for (int rt = 0; rt < 4; ++rt)
        af[(kt + 1) & 1][rt] = *(const s16x8*)&h_s[(rt * 16 + rlane) * 256 + cs];
    } else if (!LAST) {
      const unsigned short* fpn = wln + (size_t)(wc * 4) * 512 + l * 8;
#pragma unroll
      for (int c = 0; c < 4; ++c)
        wf[0][c] = *(const s16x8*)(fpn + c * 512);   // NKT even -> slot 0
    }
    __builtin_amdgcn_s_setprio(1);
#pragma unroll
    for (int rt = 0; rt < 4; ++rt)
#pragma unroll
      for (int ct = 0; ct < 4; ++ct)
        acc[rt][ct] = __builtin_amdgcn_mfma_f32_16x16x32_bf16(
            wf[kt & 1][ct], af[kt & 1][rt], acc[rt][ct], 0, 0, 0);
    __builtin_amdgcn_s_setprio(0);
  }
  // all issued ds_reads consumed by MFMAs -> raw barrier (no vmcnt drain)
  bar_raw();

  // epilogue: ReLU + pack 4 bf16 -> b64 store  (h[m][n0..n0+3])
  const int sub = (kgrp & 1) * 4;
  const int cbase = wc * 8 + (kgrp >> 1);
#pragma unroll
  for (int rt = 0; rt < 4; ++rt) {
    const int m = rt * 16 + rlane;
    const int rowb = m * 256;
#pragma unroll
    for (int ct = 0; ct < 4; ++ct) {
      const int cs = hswz(m, cbase + ct * 2);
      float v0 = fmaxf(acc[rt][ct][0], 0.f);
      float v1 = fmaxf(acc[rt][ct][1], 0.f);
      float v2 = fmaxf(acc[rt][ct][2], 0.f);
      float v3 = fmaxf(acc[rt][ct][3], 0.f);
      union { __hip_bfloat162 h2[2]; uint2 u; } pk;
      pk.h2[0] = __float22bfloat162_rn(float2{v0, v1});
      pk.h2[1] = __float22bfloat162_rn(float2{v2, v3});
      *(uint2*)&h_s[rowb + cs * 8 + sub] = pk.u;
    }
  }
  bar_lgkm();  // DS writes visible to all waves; vmcnt untouched
}

// ---------------------------------------------------------------------------
__global__ __launch_bounds__(256, 3) void hyponerf_main(
    const float* __restrict__ x, const float* __restrict__ rfreq,
    const float* __restrict__ wbout,
    const unsigned short* __restrict__ w0p, const unsigned short* __restrict__ w14p,
    const float* __restrict__ biases, float* __restrict__ out) {
  __shared__ __align__(16) unsigned short h_s[MT * 256];  // 32768 B
  __shared__ float fr_s[PE_NF * 3];
  __shared__ float x_s[MT * 3];
  __shared__ float wout_s[H + 1];

  // XCD-aware swizzle: 4096 blocks, 8 XCDs -> contiguous batches per XCD
  int bid = blockIdx.x;
  int logical = (bid & 7) * 512 + (bid >> 3);
  int b  = logical >> 8;
  int mt = logical & 255;

  int t = threadIdx.x;
  int wc = t >> 6, l = t & 63;
  int rlane = l & 15;
  int kgrp  = l >> 4;

  const unsigned short* wl0 = w0p + (size_t)b * 32768;
  const unsigned short* wl1 = w14p + (size_t)(0 * 16 + b) * 65536;
  const unsigned short* wl2 = w14p + (size_t)(1 * 16 + b) * 65536;
  const unsigned short* wl3 = w14p + (size_t)(2 * 16 + b) * 65536;
  const unsigned short* wl4 = w14p + (size_t)(3 * 16 + b) * 65536;

  // issue layer0 kt0 weight frags NOW; hides under staging + PE
  s16x8 wf[2][4];
  {
    const unsigned short* fp0 = wl0 + (size_t)(wc * 4) * 512 + l * 8;
#pragma unroll
    for (int c = 0; c < 4; ++c) wf[0][c] = *(const s16x8*)(fp0 + c * 512);
  }

  const float* xg = x + ((size_t)b * 16384 + (size_t)mt * MT) * 3;
  for (int i = t; i < MT * 3; i += 256) x_s[i] = xg[i];
  for (int i = t; i < PE_NF * 3; i += 256) fr_s[i] = rfreq[i] * 20.0f;
  for (int i = t; i < H + 1; i += 256) wout_s[i] = wbout[(size_t)b * (H + 1) + i];
  bar_lgkm();   // staging visible; vmcnt NOT drained

  // ---- Gaussian PE, chunk-owned b128 stores: thread (r = t>>2, q = t&3)
  //   covers n in [q*32, q*32+32): n<60 sin, 60..119 cos(n-60), 120..127 0.
  {
    int r = t >> 2;
    int q = t & 3;
    float x0 = x_s[r * 3 + 0], x1 = x_s[r * 3 + 1], x2 = x_s[r * 3 + 2];
    int rowb = r * 256;
#pragma unroll
    for (int cc = 0; cc < 4; ++cc) {
      int ch = q * 4 + cc;
      union { unsigned short us[8]; s16x8 v; } pk;
#pragma unroll
      for (int j = 0; j < 8; ++j) {
        int n = ch * 8 + j;
        float v = 0.f;
        if (n < 60) {
          float kv = x0 * fr_s[n * 3] + x1 * fr_s[n * 3 + 1] + x2 * fr_s[n * 3 + 2];
          v = __sinf(kv);
        } else if (n < 120) {
          int f = n - 60;
          float kv = x0 * fr_s[f * 3] + x1 * fr_s[f * 3 + 1] + x2 * fr_s[f * 3 + 2];
          v = __cosf(kv);
        }
        pk.us[j] = f2bf(v);
      }
      *(s16x8*)&h_s[rowb + hswz(r, ch) * 8] = pk.v;
    }
  }
  bar_lgkm();   // PE writes visible; layer0 frags still in flight

  // ---- 5 fused Linear+ReLU layers (wf carries next layer's kt0 frags)
  mlp_layer<4, false>(wl0, wl1, biases + (size_t)(0 * 16 + b) * H, h_s,
                      rlane, kgrp, wc, l, wf);
  mlp_layer<8, false>(wl1, wl2, biases + (size_t)(1 * 16 + b) * H, h_s,
                      rlane, kgrp, wc, l, wf);
  mlp_layer<8, false>(wl2, wl3, biases + (size_t)(2 * 16 + b) * H, h_s,
                      rlane, kgrp, wc, l, wf);
  mlp_layer<8, false>(wl3, wl4, biases + (size_t)(3 * 16 + b) * H, h_s,
                      rlane, kgrp, wc, l, wf);
  mlp_layer<8, true >(wl4, wl4, biases + (size_t)(4 * 16 + b) * H, h_s,
                      rlane, kgrp, wc, l, wf);

  // ---- final projection: out[r] = h[r][:] . wout + bias_out
  {
    int r = t >> 2;
    int q = t & 3;
    int rowb = r * 256;
    float sum = 0.f;
#pragma unroll
    for (int c = 0; c < 8; ++c) {
      int ch = q * 8 + c;
      const s16x8 hv = *(const s16x8*)&h_s[rowb + hswz(r, ch) * 8];
#pragma unroll
      for (int j = 0; j < 8; ++j)
        sum += bf2f((unsigned short)hv[j]) * wout_s[ch * 8 + j];
    }
    sum += __shfl_xor(sum, 1);
    sum += __shfl_xor(sum, 2);
    if (q == 0)
      out[(size_t)b * 16384 + (size_t)mt * MT + r] = sum + wout_s[H];
  }
}

// ---------------------------------------------------------------------------
extern "C" void kernel_launch(void* const* d_in, const int* in_sizes, int n_in,
                              void* d_out, int out_size, void* d_ws, size_t ws_size,
                              hipStream_t stream) {
  const float* x     = (const float*)d_in[0];
  const float* wb0   = (const float*)d_in[1];
  const float* wb1   = (const float*)d_in[2];
  const float* wb2   = (const float*)d_in[3];
  const float* wb3   = (const float*)d_in[4];
  const float* wb4   = (const float*)d_in[5];
  const float* wbout = (const float*)d_in[6];
  const float* rfreq = (const float*)d_in[7];
  float* out = (float*)d_out;

  char* ws = (char*)d_ws;
  unsigned short* w0p  = (unsigned short*)ws;                                // 16 x 32768 bf16
  unsigned short* w14p = (unsigned short*)(ws + (size_t)16 * 32768 * 2);     // 64 x 65536 bf16
  float* biases = (float*)(ws + (size_t)16 * 32768 * 2
                              + (size_t)64 * 65536 * 2);                     // [5][16][256] f32

  prep_weights<<<dim3(8, 8, 80), 256, 0, stream>>>(wb0, wb1, wb2, wb3, wb4,
                                                   w0p, w14p, biases);
  hyponerf_main<<<dim3(4096), 256, 0, stream>>>(x, rfreq, wbout, w0p, w14p,
                                                biases, out);
}

// Round 10
// 165.727 us; speedup vs baseline: 1.2344x; 1.0313x over previous
//
#include <hip/hip_runtime.h>
#include <hip/hip_bf16.h>

// HypoNerf fused MLP on MI355X (gfx950). R10 = R9 + VALU-cut package.
//  R9 analysis: MfmaUtil 39.5 + VALUBusy 48.7 = issue-saturated; VALU is
//  ~2-3x the algorithmic need. Fixes:
//  (1) weight loads: advancing base pointer (+16KB/kt, 2 VALU) so all loads
//      use <=3KB immediate offsets (was: 64-bit add chains per load, since
//      frag offsets up to 128KB exceed the +-4KB global imm range)
//  (2) h ds_reads: hswz(r,c+8)==hswz(r,c)+8 -> 2 base VGPRs (kt parity) +
//      compile-time imm; zero per-kt address VALU
//  (3) final projection folded into layer4 epilogue: per-lane f32 dot with
//      preloaded wout regs + shfl_xor reduce + tiny psum gather. Removes
//      layer4 h stores, one barrier, and the conflict-heavy final reads.

#define H 256
#define MT 64
#define PE_NF 60

typedef __attribute__((ext_vector_type(8))) short s16x8;   // 8 bf16
typedef __attribute__((ext_vector_type(4))) float f32x4;   // MFMA acc

static __device__ __forceinline__ unsigned short f2bf(float v) {
  unsigned int u = __float_as_uint(v);
  return (unsigned short)((u + 0x7FFFu + ((u >> 16) & 1u)) >> 16);
}
// swizzled 16B-chunk index within a 256-elem (32-chunk) row
static __device__ __forceinline__ int hswz(int row, int chunk) {
  return (chunk & ~7) | ((chunk ^ row) & 7);
}

// raw barrier: does NOT drain vmcnt (keeps global prefetch in flight).
static __device__ __forceinline__ void bar_raw() {
  asm volatile("s_barrier" ::: "memory");
}
static __device__ __forceinline__ void bar_lgkm() {
  asm volatile("s_waitcnt lgkmcnt(0)\n\ts_barrier" ::: "memory");
}

// ---------------------------------------------------------------------------
// Prep: wb (fp32, [K+1][H], last row bias) -> fragment-packed bf16.
// pack elem idx for (n, k):  (kt*16 + (n>>4))*512 + (kgrp*16 + (n&15))*8 + j
//   where kt=k>>5, kgrp=(k>>3)&3, j=k&7.   (unchanged from R9)
// ---------------------------------------------------------------------------
__global__ __launch_bounds__(256) void prep_weights(
    const float* __restrict__ wb0, const float* __restrict__ wb1,
    const float* __restrict__ wb2, const float* __restrict__ wb3,
    const float* __restrict__ wb4,
    unsigned short* __restrict__ w0p, unsigned short* __restrict__ w14p,
    float* __restrict__ biases) {
  int z = blockIdx.z;
  int li = z >> 4, b = z & 15;
  int k0 = blockIdx.x * 32;
  int n0 = blockIdx.y * 32;
  int Ks;
  const float* src;
  unsigned short* dst;
  if (li == 0) {
    Ks = 120;
    if (k0 >= 128) return;
    src = wb0 + (size_t)b * 121 * H;
    dst = w0p + (size_t)b * 32768;
  } else {
    Ks = 256;
    const float* srcs[4] = {wb1, wb2, wb3, wb4};
    src = srcs[li - 1] + (size_t)b * 257 * H;
    dst = w14p + ((size_t)(li - 1) * 16 + b) * 65536;
  }
  __shared__ float tile[32][33];
  int t = threadIdx.x;
  int tx = t & 31, ty = t >> 5;
#pragma unroll
  for (int i = 0; i < 4; ++i) {
    int k = k0 + ty + i * 8;
    tile[ty + i * 8][tx] = (k < Ks) ? src[(size_t)k * H + n0 + tx] : 0.f;
  }
  if (k0 == 0 && ty == 0)
    biases[((size_t)li * 16 + b) * H + n0 + tx] = src[(size_t)Ks * H + n0 + tx];
  __syncthreads();
  if (t < 128) {
    int nn = t & 31, kg = t >> 5;
    int n = n0 + nn;
    int kt = k0 >> 5;
    union { unsigned short us[8]; s16x8 v; } pk;
#pragma unroll
    for (int j = 0; j < 8; ++j) pk.us[j] = f2bf(tile[kg * 8 + j][nn]);
    *(s16x8*)&dst[(size_t)(kt * 16 + (n >> 4)) * 512 + (kg * 16 + (n & 15)) * 8] = pk.v;
  }
}

// ---------------------------------------------------------------------------
// One fused Linear+ReLU layer. Wave wc: all 64 rows x cols [wc*64,+64).
// fpb: this layer's frag stream base (already incl. wc & lane offsets);
// advanced +16KB per kt so loads use imm offsets 0..3KB.
// LAST: fold output projection (no h_s write): per-lane f32 dot with wout_r,
// shfl_xor reduce over kgrp, psum[wc*64+row] write (lanes 0..15).
// ---------------------------------------------------------------------------
template <int NKT, bool LAST>
static __device__ __forceinline__ void mlp_layer(
    const char* fpb, const char* fpn, const float* __restrict__ bl,
    unsigned short* __restrict__ h_s,
    const int rlane, const int kgrp, const int wc, const int l,
    s16x8 (&wf)[2][4], const float* wout_r, float* psum) {
  static_assert((NKT & 1) == 0, "ping-pong parity needs even NKT");
  f32x4 acc[4][4];
#pragma unroll
  for (int ct = 0; ct < 4; ++ct) {
    f32x4 bini = *(const f32x4*)(bl + wc * 64 + ct * 16 + kgrp * 4);
#pragma unroll
    for (int rt = 0; rt < 4; ++rt) acc[rt][ct] = bini;
  }

  // h ds_read bases: parity trick hswz(r, c+8) = hswz(r, c) + 8
  const char* hb = (const char*)h_s;
  const unsigned be = rlane * 512 + hswz(rlane, kgrp) * 16;
  const unsigned bo = rlane * 512 + hswz(rlane, 4 + kgrp) * 16;

  // h-fragment double buffer: kt0
  s16x8 af[2][4];
#pragma unroll
  for (int rt = 0; rt < 4; ++rt)
    af[0][rt] = *(const s16x8*)(hb + be + rt * 8192);

#pragma unroll
  for (int kt = 0; kt < NKT; ++kt) {
    if (kt + 1 < NKT) {
      fpb += 16384;  // 16 frags x 1KB -> next kt
#pragma unroll
      for (int c = 0; c < 4; ++c)
        wf[(kt + 1) & 1][c] = *(const s16x8*)(fpb + c * 1024);
      const unsigned base = ((kt + 1) & 1) ? bo : be;
      const unsigned off = ((kt + 1) >> 1) * 128;
#pragma unroll
      for (int rt = 0; rt < 4; ++rt)
        af[(kt + 1) & 1][rt] = *(const s16x8*)(hb + base + off + rt * 8192);
    } else if (!LAST) {
#pragma unroll
      for (int c = 0; c < 4; ++c)
        wf[0][c] = *(const s16x8*)(fpn + c * 1024);   // NKT even -> slot 0
    }
    __builtin_amdgcn_s_setprio(1);
#pragma unroll
    for (int rt = 0; rt < 4; ++rt)
#pragma unroll
      for (int ct = 0; ct < 4; ++ct)
        acc[rt][ct] = __builtin_amdgcn_mfma_f32_16x16x32_bf16(
            wf[kt & 1][ct], af[kt & 1][rt], acc[rt][ct], 0, 0, 0);
    __builtin_amdgcn_s_setprio(0);
  }

  if constexpr (LAST) {
    // fold output projection: p[rt] = sum_n relu(h[m][n]) * wout[n]
    float p[4];
#pragma unroll
    for (int rt = 0; rt < 4; ++rt) {
      float s = 0.f;
#pragma unroll
      for (int ct = 0; ct < 4; ++ct)
#pragma unroll
        for (int g = 0; g < 4; ++g)
          s += fmaxf(acc[rt][ct][g], 0.f) * wout_r[ct * 4 + g];
      s += __shfl_xor(s, 16);
      s += __shfl_xor(s, 32);
      p[rt] = s;
    }
    if (l < 16) {
#pragma unroll
      for (int rt = 0; rt < 4; ++rt)
        psum[wc * 64 + rt * 16 + l] = p[rt];
    }
  } else {
    // all issued ds_reads consumed by MFMAs -> raw barrier (no vmcnt drain)
    bar_raw();
    // epilogue: ReLU + pack 4 bf16 -> b64 store  (h[m][n0..n0+3])
    const int sub = (kgrp & 1) * 4;
    const int cbase = wc * 8 + (kgrp >> 1);
#pragma unroll
    for (int rt = 0; rt < 4; ++rt) {
      const int m = rt * 16 + rlane;
      const int rowb = m * 256;
#pragma unroll
      for (int ct = 0; ct < 4; ++ct) {
        const int cs = hswz(m, cbase + ct * 2);
        float v0 = fmaxf(acc[rt][ct][0], 0.f);
        float v1 = fmaxf(acc[rt][ct][1], 0.f);
        float v2 = fmaxf(acc[rt][ct][2], 0.f);
        float v3 = fmaxf(acc[rt][ct][3], 0.f);
        union { __hip_bfloat162 h2[2]; uint2 u; } pk;
        pk.h2[0] = __float22bfloat162_rn(float2{v0, v1});
        pk.h2[1] = __float22bfloat162_rn(float2{v2, v3});
        *(uint2*)&h_s[rowb + cs * 8 + sub] = pk.u;
      }
    }
    bar_lgkm();  // DS writes visible to all waves; vmcnt untouched
  }
}

// ---------------------------------------------------------------------------
__global__ __launch_bounds__(256, 3) void hyponerf_main(
    const float* __restrict__ x, const float* __restrict__ rfreq,
    const float* __restrict__ wbout,
    const unsigned short* __restrict__ w0p, const unsigned short* __restrict__ w14p,
    const float* __restrict__ biases, float* __restrict__ out) {
  __shared__ __align__(16) unsigned short h_s[MT * 256];  // 32768 B
  __shared__ float fr_s[PE_NF * 3];
  __shared__ float x_s[MT * 3];
  __shared__ float psum[4 * 64];

  // XCD-aware swizzle: 4096 blocks, 8 XCDs -> contiguous batches per XCD
  int bid = blockIdx.x;
  int logical = (bid & 7) * 512 + (bid >> 3);
  int b  = logical >> 8;
  int mt = logical & 255;

  int t = threadIdx.x;
  int wc = t >> 6, l = t & 63;
  int rlane = l & 15;
  int kgrp  = l >> 4;

  // fragment stream bases (incl. wave-col + lane offsets), in bytes
  const size_t lane_off = ((size_t)wc * 4 * 512 + l * 8) * 2;
  const char* f0 = (const char*)(w0p + (size_t)b * 32768) + lane_off;
  const char* f1 = (const char*)(w14p + (size_t)(0 * 16 + b) * 65536) + lane_off;
  const char* f2 = (const char*)(w14p + (size_t)(1 * 16 + b) * 65536) + lane_off;
  const char* f3 = (const char*)(w14p + (size_t)(2 * 16 + b) * 65536) + lane_off;
  const char* f4 = (const char*)(w14p + (size_t)(3 * 16 + b) * 65536) + lane_off;

  // issue layer0 kt0 weight frags NOW; hides under staging + PE
  s16x8 wf[2][4];
#pragma unroll
  for (int c = 0; c < 4; ++c) wf[0][c] = *(const s16x8*)(f0 + c * 1024);

  // preload wout for the folded final projection (scalar: wbout rows are
  // only 4B-aligned). lane's cols = wc*64 + ct*16 + kgrp*4 + g.
  float wout_r[16];
  {
    const float* wob = wbout + (size_t)b * (H + 1) + wc * 64 + kgrp * 4;
#pragma unroll
    for (int ct = 0; ct < 4; ++ct)
#pragma unroll
      for (int g = 0; g < 4; ++g) wout_r[ct * 4 + g] = wob[ct * 16 + g];
  }
  const float wout_bias = wbout[(size_t)b * (H + 1) + H];

  const float* xg = x + ((size_t)b * 16384 + (size_t)mt * MT) * 3;
  for (int i = t; i < MT * 3; i += 256) x_s[i] = xg[i];
  for (int i = t; i < PE_NF * 3; i += 256) fr_s[i] = rfreq[i] * 20.0f;
  bar_lgkm();   // staging visible; vmcnt NOT drained

  // ---- Gaussian PE, chunk-owned b128 stores: thread (r = t>>2, q = t&3)
  //   covers n in [q*32, q*32+32): n<60 sin, 60..119 cos(n-60), 120..127 0.
  {
    int r = t >> 2;
    int q = t & 3;
    float x0 = x_s[r * 3 + 0], x1 = x_s[r * 3 + 1], x2 = x_s[r * 3 + 2];
    int rowb = r * 256;
#pragma unroll
    for (int cc = 0; cc < 4; ++cc) {
      int ch = q * 4 + cc;
      union { unsigned short us[8]; s16x8 v; } pk;
#pragma unroll
      for (int j = 0; j < 8; ++j) {
        int n = ch * 8 + j;
        float v = 0.f;
        if (n < 60) {
          float kv = x0 * fr_s[n * 3] + x1 * fr_s[n * 3 + 1] + x2 * fr_s[n * 3 + 2];
          v = __sinf(kv);
        } else if (n < 120) {
          int f = n - 60;
          float kv = x0 * fr_s[f * 3] + x1 * fr_s[f * 3 + 1] + x2 * fr_s[f * 3 + 2];
          v = __cosf(kv);
        }
        pk.us[j] = f2bf(v);
      }
      *(s16x8*)&h_s[rowb + hswz(r, ch) * 8] = pk.v;
    }
  }
  bar_lgkm();   // PE writes visible; layer0 frags still in flight

  // ---- 5 fused Linear+ReLU layers (wf carries next layer's kt0 frags)
  const float* bb = biases + (size_t)b * H;
  mlp_layer<4, false>(f0, f1, bb + 0 * 16 * H, h_s, rlane, kgrp, wc, l, wf,
                      wout_r, psum);
  mlp_layer<8, false>(f1, f2, bb + 1 * 16 * H, h_s, rlane, kgrp, wc, l, wf,
                      wout_r, psum);
  mlp_layer<8, false>(f2, f3, bb + 2 * 16 * H, h_s, rlane, kgrp, wc, l, wf,
                      wout_r, psum);
  mlp_layer<8, false>(f3, f4, bb + 3 * 16 * H, h_s, rlane, kgrp, wc, l, wf,
                      wout_r, psum);
  mlp_layer<8, true >(f4, f4, bb + 4 * 16 * H, h_s, rlane, kgrp, wc, l, wf,
                      wout_r, psum);

  // ---- gather: out[r] = sum_wc psum[wc][r] + bias_out
  bar_lgkm();
  if (t < MT) {
    float s = psum[t] + psum[64 + t] + psum[128 + t] + psum[192 + t];
    out[(size_t)b * 16384 + (size_t)mt * MT + t] = s + wout_bias;
  }
}

// ---------------------------------------------------------------------------
extern "C" void kernel_launch(void* const* d_in, const int* in_sizes, int n_in,
                              void* d_out, int out_size, void* d_ws, size_t ws_size,
                              hipStream_t stream) {
  const float* x     = (const float*)d_in[0];
  const float* wb0   = (const float*)d_in[1];
  const float* wb1   = (const float*)d_in[2];
  const float* wb2   = (const float*)d_in[3];
  const float* wb3   = (const float*)d_in[4];
  const float* wb4   = (const float*)d_in[5];
  const float* wbout = (const float*)d_in[6];
  const float* rfreq = (const float*)d_in[7];
  float* out = (float*)d_out;

  char* ws = (char*)d_ws;
  unsigned short* w0p  = (unsigned short*)ws;                                // 16 x 32768 bf16
  unsigned short* w14p = (unsigned short*)(ws + (size_t)16 * 32768 * 2);     // 64 x 65536 bf16
  float* biases = (float*)(ws + (size_t)16 * 32768 * 2
                              + (size_t)64 * 65536 * 2);                     // [5][16][256] f32

  prep_weights<<<dim3(8, 8, 80), 256, 0, stream>>>(wb0, wb1, wb2, wb3, wb4,
                                                   w0p, w14p, biases);
  hyponerf_main<<<dim3(4096), 256, 0, stream>>>(x, rfreq, wbout, w0p, w14p,
                                                biases, out);
}